// Round 1
// 369.330 us; speedup vs baseline: 1.0323x; 1.0323x over previous
//
#include <hip/hip_runtime.h>

// Problem constants (fixed by reference setup_inputs)
#define BATCH 4
#define SEQ   4096
#define DIM   2048
#define D4    (DIM / 4)         // 512 float4 per (batch, s) row
#define GQ    2                 // 256 threads * 4 dims = 1024 dims -> 2 groups per row
#define NCHAIN (BATCH * DIM)    // 8192 independent chains

typedef __attribute__((ext_vector_type(4))) float v4f;

// ---------------- Kernel 1: per-segment aggregates (A, B) ----------------
// Segment operator: appending element (a_t, b_t): (A,B) -> (a_t*A, a_t*B + b_t)
// Explicit 8-deep register staging: 16 dwordx4 loads in flight per wave.
template<int LSEG>
__global__ __launch_bounds__(256) void k1_aggregate(
    const float4* __restrict__ a4, const float4* __restrict__ b4,
    float4* __restrict__ aggA4, float4* __restrict__ aggB4)
{
    const int c     = blockIdx.x;        // chunk index [0, NC)
    const int gq    = blockIdx.y;        // dim half
    const int batch = blockIdx.z;
    const int d4    = gq * 256 + threadIdx.x;   // float4 index within D

    unsigned base = (unsigned)(batch * SEQ + c * LSEG) * D4 + d4;

    float4 A = make_float4(1.f, 1.f, 1.f, 1.f);
    float4 B = make_float4(0.f, 0.f, 0.f, 0.f);

#pragma unroll 1
    for (int h = 0; h < LSEG / 8; ++h) {
        float4 av[8], bv[8];
        const unsigned hb = base + (unsigned)(h * 8) * D4;
#pragma unroll
        for (int i = 0; i < 8; ++i) av[i] = a4[hb + (unsigned)i * D4];
#pragma unroll
        for (int i = 0; i < 8; ++i) bv[i] = b4[hb + (unsigned)i * D4];
#pragma unroll
        for (int i = 0; i < 8; ++i) {
            B.x = fmaf(av[i].x, B.x, bv[i].x);  A.x *= av[i].x;
            B.y = fmaf(av[i].y, B.y, bv[i].y);  A.y *= av[i].y;
            B.z = fmaf(av[i].z, B.z, bv[i].z);  A.z *= av[i].z;
            B.w = fmaf(av[i].w, B.w, bv[i].w);  A.w *= av[i].w;
        }
    }
    const unsigned aidx = (unsigned)c * (NCHAIN / 4) + batch * (DIM / 4) + d4;
    aggA4[aidx] = A;
    aggB4[aidx] = B;
}

// ---------------- Kernel 2: hierarchical scan of chunk aggregates ----------------
// pref[c][chain] = state entering chunk c (h after chunks 0..c-1, seeded with h0).
// Block: 512 threads = 64 chains x 8 groups. Each thread aggregates NC/8 chunks,
// a 64-lane leader set does the 8-step seeded scan in LDS, then all threads
// re-walk their chunks writing pref. Serial dependent-load chain: 8 (LDS), not NC.
template<int NC>
__global__ __launch_bounds__(512) void k2_scan_agg(
    const float* __restrict__ aggA, const float* __restrict__ aggB,
    const float* __restrict__ h0, float* __restrict__ pref)
{
    constexpr int CPG = NC / 8;            // chunks per group
    const int lc = threadIdx.x & 63;       // local chain
    const int g  = threadIdx.x >> 6;       // group [0,8)
    const int ch = blockIdx.x * 64 + lc;   // global chain [0, NCHAIN)

    const unsigned idx0 = (unsigned)(g * CPG) * NCHAIN + (unsigned)ch;

    // Phase 1: per-thread aggregate over its CPG chunks (independent loads).
    float A = 1.f, B = 0.f;
#pragma unroll 8
    for (int i = 0; i < CPG; ++i) {
        const unsigned idx = idx0 + (unsigned)i * NCHAIN;
        const float a = aggA[idx];
        const float b = aggB[idx];
        B = fmaf(a, B, b);
        A *= a;
    }

    __shared__ float sA[8][64];
    __shared__ float sB[8][64];
    __shared__ float sH[8][64];
    sA[g][lc] = A;
    sB[g][lc] = B;
    __syncthreads();

    // Phase 2: 8-step seeded scan per chain (64 leader lanes).
    if (threadIdx.x < 64) {
        float h = h0[ch];
#pragma unroll
        for (int j = 0; j < 8; ++j) {
            sH[j][lc] = h;
            h = fmaf(sA[j][lc], h, sB[j][lc]);
        }
    }
    __syncthreads();

    // Phase 3: re-walk own chunks, writing entering-state (reloads are L2-hot).
    float h = sH[g][lc];
#pragma unroll 8
    for (int i = 0; i < CPG; ++i) {
        const unsigned idx = idx0 + (unsigned)i * NCHAIN;
        pref[idx] = h;
        h = fmaf(aggA[idx], h, aggB[idx]);
    }
}

// ---------------- Kernel 3: re-read, apply incoming state, write out ----------------
template<int LSEG>
__global__ __launch_bounds__(256) void k3_apply(
    const float4* __restrict__ a4, const float4* __restrict__ b4,
    const float4* __restrict__ pref4, float4* __restrict__ out4)
{
    const int c     = blockIdx.x;
    const int gq    = blockIdx.y;
    const int batch = blockIdx.z;
    const int d4    = gq * 256 + threadIdx.x;

    unsigned base = (unsigned)(batch * SEQ + c * LSEG) * D4 + d4;
    const unsigned aidx = (unsigned)c * (NCHAIN / 4) + batch * (DIM / 4) + d4;

    float4 h = pref4[aidx];

#pragma unroll 1
    for (int hh = 0; hh < LSEG / 8; ++hh) {
        float4 av[8], bv[8];
        const unsigned hb = base + (unsigned)(hh * 8) * D4;
#pragma unroll
        for (int i = 0; i < 8; ++i) av[i] = a4[hb + (unsigned)i * D4];
#pragma unroll
        for (int i = 0; i < 8; ++i) bv[i] = b4[hb + (unsigned)i * D4];
#pragma unroll
        for (int i = 0; i < 8; ++i) {
            h.x = fmaf(av[i].x, h.x, bv[i].x);
            h.y = fmaf(av[i].y, h.y, bv[i].y);
            h.z = fmaf(av[i].z, h.z, bv[i].z);
            h.w = fmaf(av[i].w, h.w, bv[i].w);
            // out is never re-read: keep it out of L2/L3 so a/b stay resident.
            __builtin_nontemporal_store(*(const v4f*)&h, (v4f*)&out4[hb + (unsigned)i * D4]);
        }
    }
}

// Safety-net fallback if workspace is too small: one thread per chain.
__global__ void scan_naive_kernel(
    const float* __restrict__ a, const float* __restrict__ b,
    const float* __restrict__ h0, float* __restrict__ out)
{
    const int chain = blockIdx.x * blockDim.x + threadIdx.x;
    if (chain >= NCHAIN) return;
    const int batch = chain / DIM;
    const int dim = chain % DIM;
    float h = h0[batch * DIM + dim];
    unsigned idx = (unsigned)(batch * SEQ) * DIM + dim;
    for (int s = 0; s < SEQ; ++s, idx += DIM) {
        h = fmaf(a[idx], h, b[idx]);
        out[idx] = h;
    }
}

template<int LSEG>
static void run_path(const float* a, const float* b, const float* h0,
                     float* out, float* ws, hipStream_t stream)
{
    constexpr int NC = SEQ / LSEG;
    const size_t seg_vals = (size_t)NC * NCHAIN;
    float* aggA = ws;
    float* aggB = aggA + seg_vals;
    float* pref = aggB + seg_vals;

    k1_aggregate<LSEG><<<dim3(NC, GQ, BATCH), dim3(256), 0, stream>>>(
        (const float4*)a, (const float4*)b, (float4*)aggA, (float4*)aggB);
    k2_scan_agg<NC><<<dim3(NCHAIN / 64), dim3(512), 0, stream>>>(
        aggA, aggB, h0, pref);
    k3_apply<LSEG><<<dim3(NC, GQ, BATCH), dim3(256), 0, stream>>>(
        (const float4*)a, (const float4*)b, (const float4*)pref, (float4*)out);
}

extern "C" void kernel_launch(void* const* d_in, const int* in_sizes, int n_in,
                              void* d_out, int out_size, void* d_ws, size_t ws_size,
                              hipStream_t stream) {
    const float* a  = (const float*)d_in[0];
    const float* b  = (const float*)d_in[1];
    const float* h0 = (const float*)d_in[2];
    float* out = (float*)d_out;

    const size_t need16 = 3 * (size_t)(SEQ / 16) * NCHAIN * sizeof(float); // 24 MB
    const size_t need32 = 3 * (size_t)(SEQ / 32) * NCHAIN * sizeof(float); // 12 MB

    if (ws_size >= need16) {
        run_path<16>(a, b, h0, out, (float*)d_ws, stream);
    } else if (ws_size >= need32) {
        run_path<32>(a, b, h0, out, (float*)d_ws, stream);
    } else {
        scan_naive_kernel<<<dim3((NCHAIN + 255) / 256), dim3(256), 0, stream>>>(
            a, b, h0, out);
    }
}

// Round 2
// 359.643 us; speedup vs baseline: 1.0601x; 1.0269x over previous
//
#include <hip/hip_runtime.h>

// Problem constants (fixed by reference setup_inputs)
#define BATCH 4
#define SEQ   4096
#define DIM   2048
#define D4    (DIM / 4)         // 512 float4 per (batch, s) row
#define GQ    2                 // 256 threads * 4 dims = 1024 dims -> 2 groups per row
#define NCHAIN (BATCH * DIM)    // 8192 independent chains

typedef __attribute__((ext_vector_type(4))) float v4f;

__device__ __forceinline__ float4 ld_nt(const float4* p) {
    v4f v = __builtin_nontemporal_load((const v4f*)p);
    return make_float4(v.x, v.y, v.z, v.w);
}

// ---------------- Kernel 1: per-segment aggregates (A, B) ----------------
// Segment operator: appending element (a_t, b_t): (A,B) -> (a_t*A, a_t*B + b_t)
// Processes ONE batch per dispatch so normal-load and nontemporal-load variants
// can be interleaved and A/B-compared in the same run via per-dispatch counters.
template<int LSEG, bool NT>
__device__ __forceinline__ void k1_body(
    const float4* __restrict__ a4, const float4* __restrict__ b4,
    float4* __restrict__ aggA4, float4* __restrict__ aggB4, int batch)
{
    const int c  = blockIdx.x;                  // chunk index [0, NC)
    const int gq = blockIdx.y;                  // dim half
    const int d4 = gq * 256 + threadIdx.x;      // float4 index within D

    unsigned base = (unsigned)(batch * SEQ + c * LSEG) * D4 + d4;

    float4 A = make_float4(1.f, 1.f, 1.f, 1.f);
    float4 B = make_float4(0.f, 0.f, 0.f, 0.f);
#pragma unroll 8
    for (int t = 0; t < LSEG; ++t) {
        const float4 av = NT ? ld_nt(&a4[base + (unsigned)t * D4]) : a4[base + (unsigned)t * D4];
        const float4 bv = NT ? ld_nt(&b4[base + (unsigned)t * D4]) : b4[base + (unsigned)t * D4];
        B.x = fmaf(av.x, B.x, bv.x);  A.x *= av.x;
        B.y = fmaf(av.y, B.y, bv.y);  A.y *= av.y;
        B.z = fmaf(av.z, B.z, bv.z);  A.z *= av.z;
        B.w = fmaf(av.w, B.w, bv.w);  A.w *= av.w;
    }
    // aggregates stay cached (consumed by k2 immediately): normal stores
    const unsigned aidx = (unsigned)c * (NCHAIN / 4) + batch * (DIM / 4) + d4;
    aggA4[aidx] = A;
    aggB4[aidx] = B;
}

template<int LSEG>
__global__ __launch_bounds__(256) void k1_reg(
    const float4* __restrict__ a4, const float4* __restrict__ b4,
    float4* __restrict__ aggA4, float4* __restrict__ aggB4, int batch)
{
    k1_body<LSEG, false>(a4, b4, aggA4, aggB4, batch);
}

template<int LSEG>
__global__ __launch_bounds__(256) void k1_nt(
    const float4* __restrict__ a4, const float4* __restrict__ b4,
    float4* __restrict__ aggA4, float4* __restrict__ aggB4, int batch)
{
    k1_body<LSEG, true>(a4, b4, aggA4, aggB4, batch);
}

// ---------------- Kernel 2: hierarchical scan of chunk aggregates ----------------
// pref[c][chain] = state entering chunk c (h after chunks 0..c-1, seeded with h0).
template<int NC>
__global__ __launch_bounds__(512) void k2_scan_agg(
    const float* __restrict__ aggA, const float* __restrict__ aggB,
    const float* __restrict__ h0, float* __restrict__ pref)
{
    constexpr int CPG = NC / 8;            // chunks per group
    const int lc = threadIdx.x & 63;       // local chain
    const int g  = threadIdx.x >> 6;       // group [0,8)
    const int ch = blockIdx.x * 64 + lc;   // global chain [0, NCHAIN)

    const unsigned idx0 = (unsigned)(g * CPG) * NCHAIN + (unsigned)ch;

    // Phase 1: per-thread aggregate over its CPG chunks.
    float A = 1.f, B = 0.f;
#pragma unroll 8
    for (int i = 0; i < CPG; ++i) {
        const unsigned idx = idx0 + (unsigned)i * NCHAIN;
        const float a = aggA[idx];
        const float b = aggB[idx];
        B = fmaf(a, B, b);
        A *= a;
    }

    __shared__ float sA[8][64];
    __shared__ float sB[8][64];
    __shared__ float sH[8][64];
    sA[g][lc] = A;
    sB[g][lc] = B;
    __syncthreads();

    // Phase 2: 8-step seeded scan per chain (64 leader lanes).
    if (threadIdx.x < 64) {
        float h = h0[ch];
#pragma unroll
        for (int j = 0; j < 8; ++j) {
            sH[j][lc] = h;
            h = fmaf(sA[j][lc], h, sB[j][lc]);
        }
    }
    __syncthreads();

    // Phase 3: re-walk own chunks, writing entering-state (reloads are cache-hot).
    float h = sH[g][lc];
#pragma unroll 8
    for (int i = 0; i < CPG; ++i) {
        const unsigned idx = idx0 + (unsigned)i * NCHAIN;
        pref[idx] = h;
        h = fmaf(aggA[idx], h, aggB[idx]);
    }
}

// ---------------- Kernel 3: re-read, apply incoming state, write out ----------------
template<int LSEG>
__global__ __launch_bounds__(256) void k3_apply(
    const float4* __restrict__ a4, const float4* __restrict__ b4,
    const float4* __restrict__ pref4, float4* __restrict__ out4)
{
    const int c     = blockIdx.x;
    const int gq    = blockIdx.y;
    const int batch = blockIdx.z;
    const int d4    = gq * 256 + threadIdx.x;

    unsigned base = (unsigned)(batch * SEQ + c * LSEG) * D4 + d4;
    const unsigned aidx = (unsigned)c * (NCHAIN / 4) + batch * (DIM / 4) + d4;

    float4 h = pref4[aidx];
#pragma unroll 8
    for (int t = 0; t < LSEG; ++t) {
        const float4 av = a4[base + (unsigned)t * D4];
        const float4 bv = b4[base + (unsigned)t * D4];
        h.x = fmaf(av.x, h.x, bv.x);
        h.y = fmaf(av.y, h.y, bv.y);
        h.z = fmaf(av.z, h.z, bv.z);
        h.w = fmaf(av.w, h.w, bv.w);
        // out is never re-read: keep it out of L2/L3 so a/b stay resident.
        __builtin_nontemporal_store(*(const v4f*)&h, (v4f*)&out4[base + (unsigned)t * D4]);
    }
}

// Safety-net fallback if workspace is too small: one thread per chain.
__global__ void scan_naive_kernel(
    const float* __restrict__ a, const float* __restrict__ b,
    const float* __restrict__ h0, float* __restrict__ out)
{
    const int chain = blockIdx.x * blockDim.x + threadIdx.x;
    if (chain >= NCHAIN) return;
    const int batch = chain / DIM;
    const int dim = chain % DIM;
    float h = h0[batch * DIM + dim];
    unsigned idx = (unsigned)(batch * SEQ) * DIM + dim;
    for (int s = 0; s < SEQ; ++s, idx += DIM) {
        h = fmaf(a[idx], h, b[idx]);
        out[idx] = h;
    }
}

template<int LSEG>
static void run_path(const float* a, const float* b, const float* h0,
                     float* out, float* ws, hipStream_t stream)
{
    constexpr int NC = SEQ / LSEG;
    const size_t seg_vals = (size_t)NC * NCHAIN;
    float* aggA = ws;
    float* aggB = aggA + seg_vals;
    float* pref = aggB + seg_vals;

    // Interleaved A/B: normal loads on batches 0,2; nontemporal loads on 1,3.
    // Order-balanced so launch position doesn't confound the comparison.
    k1_reg<LSEG><<<dim3(NC, GQ, 1), dim3(256), 0, stream>>>(
        (const float4*)a, (const float4*)b, (float4*)aggA, (float4*)aggB, 0);
    k1_nt<LSEG><<<dim3(NC, GQ, 1), dim3(256), 0, stream>>>(
        (const float4*)a, (const float4*)b, (float4*)aggA, (float4*)aggB, 1);
    k1_reg<LSEG><<<dim3(NC, GQ, 1), dim3(256), 0, stream>>>(
        (const float4*)a, (const float4*)b, (float4*)aggA, (float4*)aggB, 2);
    k1_nt<LSEG><<<dim3(NC, GQ, 1), dim3(256), 0, stream>>>(
        (const float4*)a, (const float4*)b, (float4*)aggA, (float4*)aggB, 3);

    k2_scan_agg<NC><<<dim3(NCHAIN / 64), dim3(512), 0, stream>>>(
        aggA, aggB, h0, pref);
    k3_apply<LSEG><<<dim3(NC, GQ, BATCH), dim3(256), 0, stream>>>(
        (const float4*)a, (const float4*)b, (const float4*)pref, (float4*)out);
}

extern "C" void kernel_launch(void* const* d_in, const int* in_sizes, int n_in,
                              void* d_out, int out_size, void* d_ws, size_t ws_size,
                              hipStream_t stream) {
    const float* a  = (const float*)d_in[0];
    const float* b  = (const float*)d_in[1];
    const float* h0 = (const float*)d_in[2];
    float* out = (float*)d_out;

    const size_t need16 = 3 * (size_t)(SEQ / 16) * NCHAIN * sizeof(float); // 24 MB
    const size_t need32 = 3 * (size_t)(SEQ / 32) * NCHAIN * sizeof(float); // 12 MB

    if (ws_size >= need16) {
        run_path<16>(a, b, h0, out, (float*)d_ws, stream);
    } else if (ws_size >= need32) {
        run_path<32>(a, b, h0, out, (float*)d_ws, stream);
    } else {
        scan_naive_kernel<<<dim3((NCHAIN + 255) / 256), dim3(256), 0, stream>>>(
            a, b, h0, out);
    }
}